// Round 2
// baseline (509.388 us; speedup 1.0000x reference)
//
#include <hip/hip_runtime.h>
#include <hip/hip_bf16.h>

typedef __bf16 bf16x8 __attribute__((ext_vector_type(8)));
typedef __bf16 bf16x4 __attribute__((ext_vector_type(4)));
typedef float f32x16 __attribute__((ext_vector_type(16)));
typedef unsigned short u16x8 __attribute__((ext_vector_type(8)));
typedef unsigned int u32x4 __attribute__((ext_vector_type(4)));

#define E_EDGES 524288
#define OUT_CR_OFF 1048576
#define OUT_MR_OFF 2621440

static __device__ __forceinline__ float bf2f_(unsigned short u) {
  unsigned int x = ((unsigned int)u) << 16;
  return __builtin_bit_cast(float, x);
}
static __device__ __forceinline__ unsigned short f2bf_(float f) {
  return __builtin_bit_cast(unsigned short, (__bf16)f);
}
static __device__ __forceinline__ unsigned int pack2_(float a, float b) {
  return ((unsigned int)f2bf_(b) << 16) | (unsigned int)f2bf_(a);
}

// ---------------------------------------------------------------------------
// Optional pre-pack (only if ws_size is big enough; 884736 bytes total).
// W1 (3x[256,512]) -> bf16 [h][t=16][kc=32][hidl=32][j=8],
//   elem = W1[kc*8+j][t*32+hidl]
// W2 (3x[512,OUT]) -> bf16 [h][kc=64][o=32 pad][j=8], elem = W2[kc*8+j][o]
// ---------------------------------------------------------------------------
__global__ void pack_weights(const float* __restrict__ lw1, const float* __restrict__ cw1,
                             const float* __restrict__ mw1,
                             const float* __restrict__ lw2, const float* __restrict__ cw2,
                             const float* __restrict__ mw2,
                             unsigned short* __restrict__ w1tp,
                             unsigned short* __restrict__ w2tp) {
  int idx = blockIdx.x * 256 + threadIdx.x;
  const int n1 = 3 * 16 * 32 * 32 * 8;  // 393216
  if (idx < n1) {
    int h = idx >> 17;
    int rem = idx & 131071;
    int t = rem >> 13;
    int rem2 = rem & 8191;
    int kc = rem2 >> 8;
    int rem3 = rem2 & 255;
    int hidl = rem3 >> 3;
    int j = rem3 & 7;
    const float* w1 = (h == 0) ? lw1 : (h == 1) ? cw1 : mw1;
    w1tp[idx] = f2bf_(w1[(kc * 8 + j) * 512 + t * 32 + hidl]);
  } else {
    int i2 = idx - n1;
    if (i2 < 3 * 64 * 32 * 8) {  // 49152
      int h = i2 >> 14;
      int rem = i2 & 16383;
      int kc = rem >> 8;
      int rem2 = rem & 255;
      int o = rem2 >> 3;
      int j = rem2 & 7;
      const float* w2 = (h == 0) ? lw2 : (h == 1) ? cw2 : mw2;
      int OUTD = (h == 0) ? 4 : (h == 1) ? 6 : 17;
      w2tp[i2] = (o < OUTD) ? f2bf_(w2[(kc * 8 + j) * OUTD + o]) : (unsigned short)0;
    }
  }
}

// ---------------------------------------------------------------------------
// Fully fused: one block per graph. GCN (2 layers, emb stays in LDS) then
// pair-gather + 3 MLP heads via MFMA. 512 threads = 8 waves; each wave owns
// 64 pairs (2 groups of 32). Zero d_ws use when !PACKED.
// ---------------------------------------------------------------------------
template <bool PACKED>
__launch_bounds__(512, 2)
__global__ void fused_gcn_heads(
    const float* __restrict__ x,
    const int* __restrict__ esrc, const int* __restrict__ edst,
    const int* __restrict__ pairs,
    const float* __restrict__ gw1, const float* __restrict__ gb1,
    const float* __restrict__ gw2, const float* __restrict__ gb2,
    const float* __restrict__ lw1, const float* __restrict__ lb1,
    const float* __restrict__ lw2, const float* __restrict__ lb2,
    const float* __restrict__ cw1, const float* __restrict__ cb1,
    const float* __restrict__ cw2, const float* __restrict__ cb2,
    const float* __restrict__ mw1, const float* __restrict__ mb1,
    const float* __restrict__ mw2, const float* __restrict__ mb2,
    const unsigned short* __restrict__ w1tp,
    const unsigned short* __restrict__ w2tp,
    float* __restrict__ out) {
  __shared__ unsigned short bufM[64 * 256];                // 32 KB (x/h/emb bf16)
  __shared__ __align__(16) unsigned short w1tile[8192];    // 16 KB
  __shared__ __align__(16) unsigned short w2tile[1024];    // 2 KB
  __shared__ float b1s[512];                               // 2 KB
  __shared__ __align__(16) short eS[1024], eD[1024];       // 4 KB
  __shared__ short csr[1024];                              // 2 KB
  __shared__ int csroff[65];
  __shared__ float invdeg[64], rdeg[64];

  const int b = blockIdx.x, tid = threadIdx.x;
  const int wv = tid >> 6, lane = tid & 63;

  {  // stage x (bf16) + graph-local edges
    const float4* xg = (const float4*)(x + b * (64 * 256));
    for (int i = tid; i < 4096; i += 512) {
      float4 v = xg[i];
      ushort4 o;
      o.x = f2bf_(v.x); o.y = f2bf_(v.y); o.z = f2bf_(v.z); o.w = f2bf_(v.w);
      *(ushort4*)&bufM[i * 4] = o;
    }
    const int eb = b * 1024, nb = b * 64;
    for (int i = tid; i < 1024; i += 512) {
      eS[i] = (short)(esrc[eb + i] - nb);
      eD[i] = (short)(edst[eb + i] - nb);
    }
  }
  __syncthreads();

  if (tid < 64) {  // wave 0: degree count + exclusive scan + deterministic CSR
    const short n = (short)tid;
    int cnt = 0;
    for (int c = 0; c < 128; ++c) {
      const u16x8 dv = *(const u16x8*)&eD[c * 8];
#pragma unroll
      for (int j = 0; j < 8; ++j) cnt += ((short)dv[j] == n) ? 1 : 0;
    }
    int val = cnt;
#pragma unroll
    for (int off = 1; off < 64; off <<= 1) {
      int up = __shfl_up(val, off, 64);
      if (tid >= off) val += up;
    }
    csroff[tid] = val - cnt;
    if (tid == 63) csroff[64] = val;
    const float dg = (float)(cnt + 1);  // + self-loop
    invdeg[tid] = 1.0f / dg;
    rdeg[tid] = rsqrtf(dg);
    int pos = val - cnt;
    for (int c = 0; c < 128; ++c) {
      const u16x8 dv = *(const u16x8*)&eD[c * 8];
      const u16x8 sv = *(const u16x8*)&eS[c * 8];
#pragma unroll
      for (int j = 0; j < 8; ++j)
        if ((short)dv[j] == n) csr[pos++] = (short)sv[j];
    }
  }
  __syncthreads();

  float4 acc[8];  // 8 nodes/wave x 4 feature-cols/lane

  auto do_agg = [&]() {
#pragma unroll
    for (int k = 0; k < 8; ++k) {
      const int n = wv * 8 + k;
      const ushort4 xv = *(const ushort4*)&bufM[n * 256 + lane * 4];
      const float sd = invdeg[n];
      float ax = bf2f_(xv.x) * sd, ay = bf2f_(xv.y) * sd;
      float az = bf2f_(xv.z) * sd, aw = bf2f_(xv.w) * sd;
      const float rn = rdeg[n];
      const int eb0 = csroff[n], eb1 = csroff[n + 1];
      for (int e = eb0; e < eb1; ++e) {
        const int s = csr[e];
        const float wgt = rn * rdeg[s];
        const ushort4 sv = *(const ushort4*)&bufM[s * 256 + lane * 4];
        ax += bf2f_(sv.x) * wgt; ay += bf2f_(sv.y) * wgt;
        az += bf2f_(sv.z) * wgt; aw += bf2f_(sv.w) * wgt;
      }
      acc[k].x = ax; acc[k].y = ay; acc[k].z = az; acc[k].w = aw;
    }
  };

  auto writeback = [&]() {
#pragma unroll
    for (int k = 0; k < 8; ++k) {
      const int n = wv * 8 + k;
      ushort4 o;
      o.x = f2bf_(acc[k].x); o.y = f2bf_(acc[k].y);
      o.z = f2bf_(acc[k].z); o.w = f2bf_(acc[k].w);
      *(ushort4*)&bufM[n * 256 + lane * 4] = o;
    }
  };

  auto do_matmul = [&](const float* __restrict__ W, const float* __restrict__ bias,
                       bool relu) {
#pragma unroll
    for (int k = 0; k < 8; ++k) { acc[k].x = 0.f; acc[k].y = 0.f; acc[k].z = 0.f; acc[k].w = 0.f; }
    for (int d0 = 0; d0 < 256; d0 += 8) {
      float4 wr[8];
#pragma unroll
      for (int r = 0; r < 8; ++r) wr[r] = ((const float4*)(W + (d0 + r) * 256))[lane];
#pragma unroll
      for (int k = 0; k < 8; ++k) {
        const int n = wv * 8 + k;
        const u16x8 m8 = *(const u16x8*)&bufM[n * 256 + d0];
#pragma unroll
        for (int r = 0; r < 8; ++r) {
          const float s = bf2f_(m8[r]);
          acc[k].x += wr[r].x * s; acc[k].y += wr[r].y * s;
          acc[k].z += wr[r].z * s; acc[k].w += wr[r].w * s;
        }
      }
    }
    const float4 bb = ((const float4*)bias)[lane];
#pragma unroll
    for (int k = 0; k < 8; ++k) {
      acc[k].x += bb.x; acc[k].y += bb.y; acc[k].z += bb.z; acc[k].w += bb.w;
      if (relu) {
        acc[k].x = fmaxf(acc[k].x, 0.f); acc[k].y = fmaxf(acc[k].y, 0.f);
        acc[k].z = fmaxf(acc[k].z, 0.f); acc[k].w = fmaxf(acc[k].w, 0.f);
      }
    }
  };

  // ---- GCN: 2 x (aggregate -> dense) ----
  do_agg();
  __syncthreads(); writeback(); __syncthreads();
  do_matmul(gw1, gb1, true);
  __syncthreads(); writeback(); __syncthreads();
  do_agg();
  __syncthreads(); writeback(); __syncthreads();
  do_matmul(gw2, gb2, false);
  __syncthreads(); writeback(); __syncthreads();
  // bufM now holds emb (bf16). Not modified below.

  // ---- pair heads ----
  const int half = lane >> 5, ln = lane & 31;

  // ci B-fragments for 2 pair-groups: lane holds pair=ln, d = s*16 + half*8 + j
  bf16x8 ci[2][16];
#pragma unroll
  for (int pg = 0; pg < 2; ++pg) {
    const int p = wv * 64 + pg * 32 + ln;
    const int2 pr = ((const int2*)pairs)[b * 512 + p];
    const unsigned short* e0 = &bufM[pr.x * 256];
    const unsigned short* e1 = &bufM[pr.y * 256];
#pragma unroll
    for (int s = 0; s < 16; ++s) {
      const int ko = s * 16 + half * 8;
      const u16x8 r0 = *(const u16x8*)(e0 + ko);
      const u16x8 r1 = *(const u16x8*)(e1 + ko);
      bf16x8 v;
#pragma unroll
      for (int j = 0; j < 8; ++j) v[j] = (__bf16)(0.5f * (bf2f_(r0[j]) + bf2f_(r1[j])));
      ci[pg][s] = v;
    }
  }

  for (int h = 0; h < 3; ++h) {
    const float* w1p = (h == 0) ? lw1 : (h == 1) ? cw1 : mw1;
    const float* w2p = (h == 0) ? lw2 : (h == 1) ? cw2 : mw2;
    const float* b1p = (h == 0) ? lb1 : (h == 1) ? cb1 : mb1;
    const float* b2p = (h == 0) ? lb2 : (h == 1) ? cb2 : mb2;
    const int OUTD = (h == 0) ? 4 : (h == 1) ? 6 : 17;
    float* outp = out + ((h == 0) ? 0 : (h == 1) ? OUT_CR_OFF : OUT_MR_OFF);

    __syncthreads();       // prior-head b1s readers done
    b1s[tid] = b1p[tid];   // covered by the t=0 barrier below

    f32x16 acc2[2];
#pragma unroll
    for (int i = 0; i < 16; ++i) { acc2[0][i] = 0.f; acc2[1][i] = 0.f; }

    for (int t = 0; t < 16; ++t) {
      __syncthreads();  // prior tile's readers done
      if (PACKED) {
        const float4* g1 = ((const float4*)w1tp) + (h * 16 + t) * 1024;
        float4* d1 = (float4*)w1tile;
        d1[tid] = g1[tid];
        d1[tid + 512] = g1[tid + 512];
        if (tid < 128)
          ((float4*)w2tile)[tid] = ((const float4*)w2tp)[(h * 64 + t * 4) * 32 + tid];
      } else {
        // W1 tile: thread -> (hidl, kc2); 2 kc rows of 8 strided fp32 each.
        const int hidl = tid & 31, kc2 = tid >> 5;  // kc2 in [0,16)
#pragma unroll
        for (int r = 0; r < 2; ++r) {
          const int kc = kc2 * 2 + r;
          bf16x8 v;
#pragma unroll
          for (int j = 0; j < 8; ++j)
            v[j] = (__bf16)w1p[(kc * 8 + j) * 512 + t * 32 + hidl];
          *(bf16x8*)&w1tile[(kc * 32 + hidl) * 8] = v;
        }
        // W2 slice (kc = t*4 .. t*4+4): 1024 elems by first 256 threads.
        if (tid < 256) {
          const int q = tid >> 6, rem = tid & 63, o = rem >> 1, jh = rem & 1;
          bf16x4 v;
#pragma unroll
          for (int jj = 0; jj < 4; ++jj) {
            const int row = (t * 4 + q) * 8 + jh * 4 + jj;
            v[jj] = (o < OUTD) ? (__bf16)w2p[row * OUTD + o] : (__bf16)0.f;
          }
          *(bf16x4*)&w2tile[(q * 32 + o) * 8 + jh * 4] = v;
        }
      }
      __syncthreads();

#pragma unroll
      for (int pg = 0; pg < 2; ++pg) {
        f32x16 acc1;
#pragma unroll
        for (int i = 0; i < 16; ++i) acc1[i] = 0.f;
#pragma unroll
        for (int s = 0; s < 16; ++s) {
          const bf16x8 a = *(const bf16x8*)&w1tile[((2 * s + half) * 32 + ln) * 8];
          acc1 = __builtin_amdgcn_mfma_f32_32x32x16_bf16(a, ci[pg][s], acc1, 0, 0, 0);
        }
        float hv[16];
#pragma unroll
        for (int i = 0; i < 16; ++i) {
          const int row = (i & 3) + 8 * (i >> 2) + 4 * half;
          hv[i] = fmaxf(acc1[i] + b1s[t * 32 + row], 0.f);
        }
#pragma unroll
        for (int ks = 0; ks < 2; ++ks) {
          const int bse = ks * 8;
          const unsigned x0 = pack2_(hv[bse + 0], hv[bse + 1]);
          const unsigned x1 = pack2_(hv[bse + 2], hv[bse + 3]);
          const unsigned y0 = pack2_(hv[bse + 4], hv[bse + 5]);
          const unsigned y1 = pack2_(hv[bse + 6], hv[bse + 7]);
          const unsigned px0 = __shfl_xor(x0, 32);
          const unsigned px1 = __shfl_xor(x1, 32);
          const unsigned py0 = __shfl_xor(y0, 32);
          const unsigned py1 = __shfl_xor(y1, 32);
          u32x4 wt;
          wt[0] = half ? py0 : x0;
          wt[1] = half ? py1 : x1;
          wt[2] = half ? y0 : px0;
          wt[3] = half ? y1 : px1;
          const bf16x8 bfrag = __builtin_bit_cast(bf16x8, wt);
          const bf16x8 a2 = *(const bf16x8*)&w2tile[((ks * 2 + half) * 32 + ln) * 8];
          acc2[pg] = __builtin_amdgcn_mfma_f32_32x32x16_bf16(a2, bfrag, acc2[pg], 0, 0, 0);
        }
      }
    }

    // epilogue: acc2 reg i -> out[o=(i&3)+8*(i>>2)+4*half][pair]
#pragma unroll
    for (int pg = 0; pg < 2; ++pg) {
      const int p = wv * 64 + pg * 32 + ln;
      const long q = (long)b * 512 + p;
#pragma unroll
      for (int g4 = 0; g4 < 4; ++g4) {
        const int o0 = g4 * 8 + 4 * half;
#pragma unroll
        for (int e = 0; e < 4; ++e) {
          const int o = o0 + e;
          if (o < OUTD) outp[q * OUTD + o] = acc2[pg][g4 * 4 + e] + b2p[o];
        }
      }
    }
  }
}

// ---------------------------------------------------------------------------
extern "C" void kernel_launch(void* const* d_in, const int* in_sizes, int n_in,
                              void* d_out, int out_size, void* d_ws, size_t ws_size,
                              hipStream_t stream) {
  (void)in_sizes; (void)n_in; (void)out_size;
  const float* x   = (const float*)d_in[0];
  const int* eidx  = (const int*)d_in[1];
  const int* pairs = (const int*)d_in[2];
  const float* gw1 = (const float*)d_in[3];
  const float* gb1 = (const float*)d_in[4];
  const float* gw2 = (const float*)d_in[5];
  const float* gb2 = (const float*)d_in[6];
  const float* lw1 = (const float*)d_in[7];
  const float* lb1 = (const float*)d_in[8];
  const float* lw2 = (const float*)d_in[9];
  const float* lb2 = (const float*)d_in[10];
  const float* cw1 = (const float*)d_in[11];
  const float* cb1 = (const float*)d_in[12];
  const float* cw2 = (const float*)d_in[13];
  const float* cb2 = (const float*)d_in[14];
  const float* mw1 = (const float*)d_in[15];
  const float* mb1 = (const float*)d_in[16];
  const float* mw2 = (const float*)d_in[17];
  const float* mb2 = (const float*)d_in[18];

  const size_t NEED = (size_t)(3 * 16 * 32 * 32 * 8 + 3 * 64 * 32 * 8) * 2;  // 884736 B
  unsigned short* w1tp = (unsigned short*)d_ws;
  unsigned short* w2tp = w1tp + 3 * 16 * 32 * 32 * 8;

  if (d_ws != nullptr && ws_size >= NEED) {
    pack_weights<<<1728, 256, 0, stream>>>(lw1, cw1, mw1, lw2, cw2, mw2, w1tp, w2tp);
    fused_gcn_heads<true><<<512, 512, 0, stream>>>(
        x, eidx, eidx + E_EDGES, pairs, gw1, gb1, gw2, gb2,
        lw1, lb1, lw2, lb2, cw1, cb1, cw2, cb2, mw1, mb1, mw2, mb2,
        w1tp, w2tp, (float*)d_out);
  } else {
    fused_gcn_heads<false><<<512, 512, 0, stream>>>(
        x, eidx, eidx + E_EDGES, pairs, gw1, gb1, gw2, gb2,
        lw1, lb1, lw2, lb2, cw1, cb1, cw2, cb2, mw1, mb1, mw2, mb2,
        w1tp, w2tp, (float*)d_out);
  }
}

// Round 3
// 426.587 us; speedup vs baseline: 1.1941x; 1.1941x over previous
//
#include <hip/hip_runtime.h>
#include <hip/hip_bf16.h>

typedef __bf16 bf16x8 __attribute__((ext_vector_type(8)));
typedef __bf16 bf16x4 __attribute__((ext_vector_type(4)));
typedef float f32x16 __attribute__((ext_vector_type(16)));
typedef unsigned short u16x8 __attribute__((ext_vector_type(8)));
typedef unsigned int u32x4 __attribute__((ext_vector_type(4)));

#define E_EDGES 524288
#define OUT_CR_OFF 1048576
#define OUT_MR_OFF 2621440
#define W1TP_ELEMS (48 * 9216)        // 442368 bf16 (heads blobs)
#define GCNW_ELEMS (2 * 8 * 16 * 64 * 8)  // 131072 bf16 (gcn W frags)
#define WS_NEED ((size_t)(W1TP_ELEMS + GCNW_ELEMS) * 2)

static __device__ __forceinline__ float bf2f_(unsigned short u) {
  unsigned int x = ((unsigned int)u) << 16;
  return __builtin_bit_cast(float, x);
}
static __device__ __forceinline__ unsigned short f2bf_(float f) {
  return __builtin_bit_cast(unsigned short, (__bf16)f);
}
static __device__ __forceinline__ unsigned int pack2_(float a, float b) {
  return ((unsigned int)f2bf_(b) << 16) | (unsigned int)f2bf_(a);
}

// ---------------------------------------------------------------------------
// Pre-pack (PACKED path). Heads blob per (h,tt): [w1frag 8192][w2frag 1024]
//   w1frag (kc*32+hidl)*8+j       = W1[kc*8+j][tt*32+hidl]
//   w2frag 8192+(q*32+o)*8+j      = W2[(tt*4+q)*8+j][o]  (o>=OUTD -> 0)
// GCN frags: gcnw[((layer*8+O)*16+s)*512 + lane*8 + j]
//   = W[(s*16+(lane>>5)*8+j)][O*32+(lane&31)]
// ---------------------------------------------------------------------------
__global__ void pack_weights(const float* __restrict__ gw1, const float* __restrict__ gw2,
                             const float* __restrict__ lw1, const float* __restrict__ cw1,
                             const float* __restrict__ mw1,
                             const float* __restrict__ lw2, const float* __restrict__ cw2,
                             const float* __restrict__ mw2,
                             unsigned short* __restrict__ w1tp,
                             unsigned short* __restrict__ gcnw) {
  const int idx = blockIdx.x * 256 + threadIdx.x;
  if (idx < W1TP_ELEMS) {
    const int ht = idx / 9216;
    const int r = idx - ht * 9216;
    const int h = ht >> 4, tt = ht & 15;
    if (r < 8192) {
      const int kc = r >> 8, r2 = r & 255, hidl = r2 >> 3, j = r2 & 7;
      const float* w1 = (h == 0) ? lw1 : (h == 1) ? cw1 : mw1;
      w1tp[idx] = f2bf_(w1[(kc * 8 + j) * 512 + tt * 32 + hidl]);
    } else {
      const int r2 = r - 8192;
      const int q = r2 >> 8, r3 = r2 & 255, o = r3 >> 3, j = r3 & 7;
      const float* w2 = (h == 0) ? lw2 : (h == 1) ? cw2 : mw2;
      const int OUTD = (h == 0) ? 4 : (h == 1) ? 6 : 17;
      w1tp[idx] = (o < OUTD) ? f2bf_(w2[((tt * 4 + q) * 8 + j) * OUTD + o])
                             : (unsigned short)0;
    }
  } else {
    const int g = idx - W1TP_ELEMS;
    if (g < GCNW_ELEMS) {
      const int layer = g >> 16, r = g & 65535;
      const int O = r >> 13, r2 = r & 8191, s = r2 >> 9;
      const int r3 = r2 & 511, lane = r3 >> 3, j = r3 & 7;
      const float* W = layer ? gw2 : gw1;
      gcnw[g] = f2bf_(W[(s * 16 + (lane >> 5) * 8 + j) * 256 + O * 32 + (lane & 31)]);
    }
  }
}

// ---------------------------------------------------------------------------
// One block per graph: GCN (MFMA dense layers, emb stays in LDS) + 3 heads.
// bufM XOR-swizzled (byte ^= (node&15)<<4) -> conflict-free node-major reads.
// ---------------------------------------------------------------------------
template <bool PACKED>
__launch_bounds__(512, 2)
__global__ void fused_gcn_heads(
    const float* __restrict__ x,
    const int* __restrict__ esrc, const int* __restrict__ edst,
    const int* __restrict__ pairs,
    const float* __restrict__ gw1, const float* __restrict__ gb1,
    const float* __restrict__ gw2, const float* __restrict__ gb2,
    const float* __restrict__ lw1, const float* __restrict__ lb1,
    const float* __restrict__ lw2, const float* __restrict__ lb2,
    const float* __restrict__ cw1, const float* __restrict__ cb1,
    const float* __restrict__ cw2, const float* __restrict__ cb2,
    const float* __restrict__ mw1, const float* __restrict__ mb1,
    const float* __restrict__ mw2, const float* __restrict__ mb2,
    const unsigned short* __restrict__ w1tp,
    const unsigned short* __restrict__ gcnw,
    float* __restrict__ out) {
  __shared__ unsigned short bufM[16384];  // 32 KB [node64][d256] bf16, swizzled
  __shared__ union WU {
    struct GG { short eS[1024]; short eD[1024]; short csr[1024]; } g;
    unsigned short wbuf[2][9216];         // 36 KB heads double-buffer
  } U;
  __shared__ int csroff[65];
  __shared__ float invdeg[64], rdeg[64];
  __shared__ float b1s[1568];             // 3x512 b1 + b2 tails

  const int b = blockIdx.x, tid = threadIdx.x;
  const int wv = tid >> 6, lane = tid & 63;
  const int half = lane >> 5, ln = lane & 31;

  auto sidx = [](int node, int boff) {  // u16 index into swizzled bufM
    return (node * 512 + (boff ^ ((node & 15) << 4))) >> 1;
  };

  {  // stage x (bf16, swizzled) + graph-local edges
    const float4* xg = (const float4*)(x + b * 16384);
    for (int i = tid; i < 4096; i += 512) {
      const float4 v = xg[i];
      ushort4 o4;
      o4.x = f2bf_(v.x); o4.y = f2bf_(v.y); o4.z = f2bf_(v.z); o4.w = f2bf_(v.w);
      *(ushort4*)&bufM[sidx(i >> 6, (i & 63) * 8)] = o4;
    }
    const int eb = b * 1024, nb = b * 64;
    for (int i = tid; i < 1024; i += 512) {
      U.g.eS[i] = (short)(esrc[eb + i] - nb);
      U.g.eD[i] = (short)(edst[eb + i] - nb);
    }
  }
  __syncthreads();

  if (tid < 64) {  // wave 0: degree + scan + deterministic CSR
    const short n = (short)tid;
    int cnt = 0;
    for (int c = 0; c < 128; ++c) {
      const u16x8 dv = *(const u16x8*)&U.g.eD[c * 8];
#pragma unroll
      for (int j = 0; j < 8; ++j) cnt += ((short)dv[j] == n) ? 1 : 0;
    }
    int val = cnt;
#pragma unroll
    for (int off = 1; off < 64; off <<= 1) {
      const int up = __shfl_up(val, off, 64);
      if (tid >= off) val += up;
    }
    csroff[tid] = val - cnt;
    if (tid == 63) csroff[64] = val;
    const float dg = (float)(cnt + 1);
    invdeg[tid] = 1.0f / dg;
    rdeg[tid] = rsqrtf(dg);
    int pos = val - cnt;
    for (int c = 0; c < 128; ++c) {
      const u16x8 dv = *(const u16x8*)&U.g.eD[c * 8];
      const u16x8 sv = *(const u16x8*)&U.g.eS[c * 8];
#pragma unroll
      for (int j = 0; j < 8; ++j)
        if ((short)dv[j] == n) U.g.csr[pos++] = (short)sv[j];
    }
  }
  __syncthreads();

  float4 acc[8];

  auto do_agg = [&]() {
#pragma unroll
    for (int k = 0; k < 8; ++k) {
      const int n = wv * 8 + k;
      const ushort4 xv = *(const ushort4*)&bufM[sidx(n, lane * 8)];
      const float sd = invdeg[n];
      float ax = bf2f_(xv.x) * sd, ay = bf2f_(xv.y) * sd;
      float az = bf2f_(xv.z) * sd, aw = bf2f_(xv.w) * sd;
      const float rn = rdeg[n];
      const int e0 = csroff[n], e1 = csroff[n + 1];
      for (int e = e0; e < e1; ++e) {
        const int s = U.g.csr[e];
        const float wgt = rn * rdeg[s];
        const ushort4 sv = *(const ushort4*)&bufM[sidx(s, lane * 8)];
        ax += bf2f_(sv.x) * wgt; ay += bf2f_(sv.y) * wgt;
        az += bf2f_(sv.z) * wgt; aw += bf2f_(sv.w) * wgt;
      }
      acc[k].x = ax; acc[k].y = ay; acc[k].z = az; acc[k].w = aw;
    }
  };

  auto writeback = [&]() {
#pragma unroll
    for (int k = 0; k < 8; ++k) {
      const int n = wv * 8 + k;
      ushort4 o4;
      o4.x = f2bf_(acc[k].x); o4.y = f2bf_(acc[k].y);
      o4.z = f2bf_(acc[k].z); o4.w = f2bf_(acc[k].w);
      *(ushort4*)&bufM[sidx(n, lane * 8)] = o4;
    }
  };

  // dense layer via MFMA: D[o,node] = sum_k W[k][o] * m[node][k]
  auto do_mm = [&](int layer, const float* __restrict__ Wg,
                   const float* __restrict__ bias, bool relu) {
    f32x16 a0, a1;
#pragma unroll
    for (int i = 0; i < 16; ++i) { a0[i] = 0.f; a1[i] = 0.f; }
#pragma unroll
    for (int s = 0; s < 16; ++s) {
      bf16x8 aW;
      if (PACKED) {
        aW = *(const bf16x8*)&gcnw[(((layer * 8 + wv) * 16 + s) * 64 + lane) * 8];
      } else {
#pragma unroll
        for (int j = 0; j < 8; ++j)
          aW[j] = (__bf16)Wg[(s * 16 + half * 8 + j) * 256 + wv * 32 + ln];
      }
      const bf16x8 b0 = *(const bf16x8*)&bufM[sidx(ln, s * 32 + half * 16)];
      const bf16x8 b1v = *(const bf16x8*)&bufM[sidx(32 + ln, s * 32 + half * 16)];
      a0 = __builtin_amdgcn_mfma_f32_32x32x16_bf16(aW, b0, a0, 0, 0, 0);
      a1 = __builtin_amdgcn_mfma_f32_32x32x16_bf16(aW, b1v, a1, 0, 0, 0);
    }
    __syncthreads();  // all bufM reads done
    float4 bb[4];
#pragma unroll
    for (int g4 = 0; g4 < 4; ++g4)
      bb[g4] = *(const float4*)&bias[wv * 32 + g4 * 8 + 4 * half];
#pragma unroll
    for (int N = 0; N < 2; ++N) {
      const int node = N * 32 + ln;
#pragma unroll
      for (int g4 = 0; g4 < 4; ++g4) {
#pragma unroll
        for (int e2 = 0; e2 < 2; ++e2) {
          float v0 = (N ? a1 : a0)[g4 * 4 + e2 * 2 + 0] + bb[g4][e2 * 2 + 0];
          float v1 = (N ? a1 : a0)[g4 * 4 + e2 * 2 + 1] + bb[g4][e2 * 2 + 1];
          if (relu) { v0 = fmaxf(v0, 0.f); v1 = fmaxf(v1, 0.f); }
          const int ocol = wv * 32 + g4 * 8 + 4 * half + e2 * 2;
          *(unsigned int*)&bufM[sidx(node, ocol * 2)] = pack2_(v0, v1);
        }
      }
    }
    __syncthreads();
  };

  // ---- GCN ----
  do_agg(); __syncthreads(); writeback(); __syncthreads();
  do_mm(0, gw1, gb1, true);
  do_agg(); __syncthreads(); writeback(); __syncthreads();
  do_mm(1, gw2, gb2, false);
  // bufM = emb (bf16, swizzled), read-only below.

  // stage head biases
  b1s[tid] = lb1[tid];
  b1s[512 + tid] = cb1[tid];
  b1s[1024 + tid] = mb1[tid];
  if (tid < 4) b1s[1536 + tid] = lb2[tid];
  else if (tid < 10) b1s[1536 + tid] = cb2[tid - 4];
  else if (tid < 27) b1s[1536 + tid] = mb2[tid - 10];

  // ci fragments (2 pair-groups x full K): lane pair=ln, d = s*16+half*8+j
  bf16x8 ci[2][16];
#pragma unroll
  for (int pg = 0; pg < 2; ++pg) {
    const int p = wv * 64 + pg * 32 + ln;
    const int2 pr = ((const int2*)pairs)[b * 512 + p];
#pragma unroll
    for (int s = 0; s < 16; ++s) {
      const int boff = s * 32 + half * 16;
      const u16x8 r0 = *(const u16x8*)&bufM[sidx(pr.x, boff)];
      const u16x8 r1 = *(const u16x8*)&bufM[sidx(pr.y, boff)];
      bf16x8 v;
#pragma unroll
      for (int j = 0; j < 8; ++j) v[j] = (__bf16)(0.5f * (bf2f_(r0[j]) + bf2f_(r1[j])));
      ci[pg][s] = v;
    }
  }

  // ---- heads: 48-tile loop, reg-staged double buffer, 1 barrier/tile ----
  float4 st0, st1, st2;
  float w1r[16]; float w2r[4];
  const int hidl = tid & 31, kc2 = tid >> 5;

  auto stage_issue = [&](int ht) {
    if (PACKED) {
      const float4* g = (const float4*)(w1tp + ht * 9216);
      st0 = g[tid]; st1 = g[tid + 512];
      if (tid < 128) st2 = g[tid + 1024];
    } else {
      const int h = ht >> 4, tt = ht & 15;
      const float* w1p = (h == 0) ? lw1 : (h == 1) ? cw1 : mw1;
      const float* w2p = (h == 0) ? lw2 : (h == 1) ? cw2 : mw2;
      const int OUTD = (h == 0) ? 4 : (h == 1) ? 6 : 17;
#pragma unroll
      for (int r = 0; r < 2; ++r)
#pragma unroll
        for (int j = 0; j < 8; ++j)
          w1r[r * 8 + j] = w1p[((2 * kc2 + r) * 8 + j) * 512 + tt * 32 + hidl];
      if (tid < 256) {
        const int q4 = tid >> 6, rem = tid & 63, o = rem >> 1, jh = rem & 1;
#pragma unroll
        for (int jj = 0; jj < 4; ++jj) {
          const int row = (tt * 4 + q4) * 8 + jh * 4 + jj;
          w2r[jj] = (o < OUTD) ? w2p[row * OUTD + o] : 0.f;
        }
      }
    }
  };
  auto stage_commit = [&](int bi) {
    if (PACKED) {
      float4* d = (float4*)U.wbuf[bi];
      d[tid] = st0; d[tid + 512] = st1;
      if (tid < 128) d[tid + 1024] = st2;
    } else {
#pragma unroll
      for (int r = 0; r < 2; ++r) {
        bf16x8 v;
#pragma unroll
        for (int j = 0; j < 8; ++j) v[j] = (__bf16)w1r[r * 8 + j];
        *(bf16x8*)&U.wbuf[bi][((2 * kc2 + r) * 32 + hidl) * 8] = v;
      }
      if (tid < 256) {
        const int q4 = tid >> 6, rem = tid & 63, o = rem >> 1, jh = rem & 1;
        bf16x4 v4;
#pragma unroll
        for (int jj = 0; jj < 4; ++jj) v4[jj] = (__bf16)w2r[jj];
        *(bf16x4*)&U.wbuf[bi][8192 + (q4 * 32 + o) * 8 + jh * 4] = v4;
      }
    }
  };

  stage_issue(0);
  stage_commit(0);
  __syncthreads();

  f32x16 acc2_0, acc2_1;
  for (int ht = 0; ht < 48; ++ht) {
    const int h = ht >> 4, tt = ht & 15, cur = ht & 1;
    if (tt == 0) {
#pragma unroll
      for (int i = 0; i < 16; ++i) { acc2_0[i] = 0.f; acc2_1[i] = 0.f; }
    }
    if (ht < 47) stage_issue(ht + 1);

    f32x16 p0, p1;
#pragma unroll
    for (int i = 0; i < 16; ++i) { p0[i] = 0.f; p1[i] = 0.f; }
    __builtin_amdgcn_s_setprio(1);
#pragma unroll
    for (int s = 0; s < 16; ++s) {
      const bf16x8 a = *(const bf16x8*)&U.wbuf[cur][((2 * s + half) * 32 + ln) * 8];
      p0 = __builtin_amdgcn_mfma_f32_32x32x16_bf16(a, ci[0][s], p0, 0, 0, 0);
      p1 = __builtin_amdgcn_mfma_f32_32x32x16_bf16(a, ci[1][s], p1, 0, 0, 0);
    }
    __builtin_amdgcn_s_setprio(0);

    const bf16x8 a2k0 = *(const bf16x8*)&U.wbuf[cur][8192 + ((0 + half) * 32 + ln) * 8];
    const bf16x8 a2k1 = *(const bf16x8*)&U.wbuf[cur][8192 + ((2 + half) * 32 + ln) * 8];
    float4 bb[4];
#pragma unroll
    for (int g4 = 0; g4 < 4; ++g4)
      bb[g4] = *(const float4*)&b1s[h * 512 + tt * 32 + g4 * 8 + 4 * half];

#pragma unroll
    for (int pg = 0; pg < 2; ++pg) {
      float hv[16];
#pragma unroll
      for (int i = 0; i < 16; ++i)
        hv[i] = fmaxf((pg ? p1 : p0)[i] + bb[i >> 2][i & 3], 0.f);
#pragma unroll
      for (int ks = 0; ks < 2; ++ks) {
        const int bse = ks * 8;
        const unsigned x0 = pack2_(hv[bse + 0], hv[bse + 1]);
        const unsigned x1 = pack2_(hv[bse + 2], hv[bse + 3]);
        const unsigned y0 = pack2_(hv[bse + 4], hv[bse + 5]);
        const unsigned y1 = pack2_(hv[bse + 6], hv[bse + 7]);
        const unsigned px0 = __shfl_xor(x0, 32);
        const unsigned px1 = __shfl_xor(x1, 32);
        const unsigned py0 = __shfl_xor(y0, 32);
        const unsigned py1 = __shfl_xor(y1, 32);
        u32x4 wt;
        wt[0] = half ? py0 : x0;
        wt[1] = half ? py1 : x1;
        wt[2] = half ? y0 : px0;
        wt[3] = half ? y1 : px1;
        const bf16x8 bfrag = __builtin_bit_cast(bf16x8, wt);
        if (pg == 0)
          acc2_0 = __builtin_amdgcn_mfma_f32_32x32x16_bf16(ks ? a2k1 : a2k0, bfrag,
                                                           acc2_0, 0, 0, 0);
        else
          acc2_1 = __builtin_amdgcn_mfma_f32_32x32x16_bf16(ks ? a2k1 : a2k0, bfrag,
                                                           acc2_1, 0, 0, 0);
      }
    }

    if (ht < 47) stage_commit(cur ^ 1);
    __syncthreads();

    if (tt == 15) {
      const int OUTD = (h == 0) ? 4 : (h == 1) ? 6 : 17;
      float* outp = out + ((h == 0) ? 0 : (h == 1) ? OUT_CR_OFF : OUT_MR_OFF);
      const int b2o = (h == 0) ? 1536 : (h == 1) ? 1540 : 1546;
#pragma unroll
      for (int pg = 0; pg < 2; ++pg) {
        const long qq = (long)b * 512 + wv * 64 + pg * 32 + ln;
#pragma unroll
        for (int g4 = 0; g4 < 4; ++g4) {
#pragma unroll
          for (int e = 0; e < 4; ++e) {
            const int o = g4 * 8 + 4 * half + e;
            if (o < OUTD)
              outp[qq * OUTD + o] = (pg ? acc2_1 : acc2_0)[g4 * 4 + e] + b1s[b2o + o];
          }
        }
      }
    }
  }
}

// ---------------------------------------------------------------------------
extern "C" void kernel_launch(void* const* d_in, const int* in_sizes, int n_in,
                              void* d_out, int out_size, void* d_ws, size_t ws_size,
                              hipStream_t stream) {
  (void)in_sizes; (void)n_in; (void)out_size;
  const float* x   = (const float*)d_in[0];
  const int* eidx  = (const int*)d_in[1];
  const int* pairs = (const int*)d_in[2];
  const float* gw1 = (const float*)d_in[3];
  const float* gb1 = (const float*)d_in[4];
  const float* gw2 = (const float*)d_in[5];
  const float* gb2 = (const float*)d_in[6];
  const float* lw1 = (const float*)d_in[7];
  const float* lb1 = (const float*)d_in[8];
  const float* lw2 = (const float*)d_in[9];
  const float* lb2 = (const float*)d_in[10];
  const float* cw1 = (const float*)d_in[11];
  const float* cb1 = (const float*)d_in[12];
  const float* cw2 = (const float*)d_in[13];
  const float* cb2 = (const float*)d_in[14];
  const float* mw1 = (const float*)d_in[15];
  const float* mb1 = (const float*)d_in[16];
  const float* mw2 = (const float*)d_in[17];
  const float* mb2 = (const float*)d_in[18];

  unsigned short* w1tp = (unsigned short*)d_ws;
  unsigned short* gcnw = w1tp + W1TP_ELEMS;

  if (d_ws != nullptr && ws_size >= WS_NEED) {
    pack_weights<<<2240, 256, 0, stream>>>(gw1, gw2, lw1, cw1, mw1, lw2, cw2, mw2,
                                           w1tp, gcnw);
    fused_gcn_heads<true><<<512, 512, 0, stream>>>(
        x, eidx, eidx + E_EDGES, pairs, gw1, gb1, gw2, gb2,
        lw1, lb1, lw2, lb2, cw1, cb1, cw2, cb2, mw1, mb1, mw2, mb2,
        w1tp, gcnw, (float*)d_out);
  } else {
    fused_gcn_heads<false><<<512, 512, 0, stream>>>(
        x, eidx, eidx + E_EDGES, pairs, gw1, gb1, gw2, gb2,
        lw1, lb1, lw2, lb2, cw1, cb1, cw2, cb2, mw1, mb1, mw2, mb2,
        w1tp, gcnw, (float*)d_out);
  }
}